// Round 12
// baseline (211.591 us; speedup 1.0000x reference)
//
#include <hip/hip_runtime.h>
#include <hip/hip_fp16.h>

// ---------------------------------------------------------------------------
// 2-layer tanh RNN, B=8192, S=512, H=16. MFMA 16x16x16_f16 producer/consumer
// pipeline (chunked K=16 handoff, round-11 structure VERBATIM) with a
// TRANS-FREE tanh. Cross-round evidence (r6/r7/r11 all ~440-480 cyc/step at
// ~165 issue): v_exp_f32/v_rcp_f32 dependent latency ~150cyc each dominates
// the recurrence chain. New tanh: exp2 by range reduction (rndne + deg-4
// Taylor + exponent bit-assembly) and reciprocal by magic-init + 3 Newton —
// all plain VALU, chain ~75 cyc instead of ~350.
// wave0 = layer 0, wave1 = layer 1, 32-slot LDS double buffer, 1 barrier per
// 16 steps. 512 blocks x 128 thr = 1024 waves = 1/SIMD.
// ---------------------------------------------------------------------------

typedef __fp16 f16x4 __attribute__((ext_vector_type(4)));
typedef __fp16 f16x2 __attribute__((ext_vector_type(2)));
typedef float  f32x4 __attribute__((ext_vector_type(4)));

__device__ __forceinline__ float tanh_fast(float v) {
    // tanh(v) = 1 - 2/(e^{2v}+1), NO transcendental instructions.
    // e^{2v} = 2^w, w = v*2log2e; n=rndne(w), f=w-n in [-.5,.5];
    // 2^f deg-4 Taylor (rel err <4.2e-5); 2^n by exponent bits.
    // 1/D via magic init (~6% err) + 3 Newton (err ~4e-8).
    float xc = fminf(fmaxf(v, -8.0f), 8.0f);
    float w  = xc * 2.8853900817779268f;        // 2*log2(e)
    float n  = __builtin_rintf(w);              // v_rndne_f32
    float f  = w - n;
    float p  = fmaf(f, 0.009618129107628477f, 0.05550410866482158f);
    p = fmaf(f, p, 0.2402265069591007f);
    p = fmaf(f, p, 0.6931471805599453f);
    p = fmaf(f, p, 1.0f);
    const int ni = (int)n;                      // exact (n already integral)
    const float sc = __int_as_float((ni + 127) << 23);   // 2^n
    const float E  = p * sc;                    // e^{2v}
    const float D  = E + 1.0f;
    float y = __int_as_float(0x7EF0A3D7 - __float_as_int(D));
    y = y * fmaf(-D, y, 2.0f);
    y = y * fmaf(-D, y, 2.0f);
    y = y * fmaf(-D, y, 2.0f);
    return fmaf(-2.0f, y, 1.0f);
}

__global__ __launch_bounds__(128, 1) void rnn2_pipek(
    const float* __restrict__ x,
    const float* __restrict__ Wih0, const float* __restrict__ Whh0,
    const float* __restrict__ bih0, const float* __restrict__ bhh0,
    const float* __restrict__ Wih1, const float* __restrict__ Whh1,
    const float* __restrict__ bih1, const float* __restrict__ bhh1,
    const float* __restrict__ Wfc,  const float* __restrict__ bfc,
    float* __restrict__ out)
{
    const int tid  = threadIdx.x;
    const int wid  = tid >> 6;      // 0 = layer-0 producer, 1 = layer-1 consumer
    const int lane = tid & 63;
    const int q    = lane >> 4;     // quarter: k-slot / C-row group
    const int col  = lane & 15;     // batch column n; also A row m
    const int m4   = q * 4;
    const int b0   = blockIdx.x * 16;

    // H0 handoff: B-fragments (8B/lane), 32 slots = 2 chunks of 16 (16 KB)
    __shared__ unsigned long long h0slot[32][64];

    // A fragments: A[m][k], m = col, k = m4 + i  (f16 RNE)
    f16x4 Ahh0, Aih1, Ahh1;
#pragma unroll
    for (int i = 0; i < 4; ++i) {
        Ahh0[i] = (__fp16)Whh0[col * 16 + m4 + i];
        Aih1[i] = (__fp16)Wih1[col * 16 + m4 + i];
        Ahh1[i] = (__fp16)Whh1[col * 16 + m4 + i];
    }
    // per-lane constants for C rows m = m4 + r
    float wih0q[4], b0q[4], wfcq[4];
    f32x4 cb1;
#pragma unroll
    for (int r = 0; r < 4; ++r) {
        wih0q[r] = Wih0[m4 + r];                    // W_ih0 is [16][1]
        b0q[r]   = bih0[m4 + r] + bhh0[m4 + r];
        cb1[r]   = bih1[m4 + r] + bhh1[m4 + r];
        wfcq[r]  = Wfc[m4 + r];
    }
    const float* __restrict__ xrow = x + (size_t)(b0 + col) * 512;
    const f32x4 zero4 = {0.f, 0.f, 0.f, 0.f};

    // producer state (H0[-1] = 0 -> first mfma passes c0 through)
    f16x4 Bh0 = {0, 0, 0, 0};
    float xc[16], xn[16];
    // consumer state
    f16x4 h0cur, Bh1 = {0, 0, 0, 0};
    float u0 = 0.f, u1 = 0.f, u2 = 0.f, u3 = 0.f;

    if (wid == 0) {
#pragma unroll
        for (int i = 0; i < 16; ++i) xc[i] = xrow[i];
    }

    // body i: producer runs chunk i (i<32), consumer runs chunk i-1 (i>=1).
    // One barrier per body. Consumer only reads slots written before the
    // previous barrier (producer leads by exactly one 16-step chunk).
    for (int i = 0; i <= 32; ++i) {
        if (wid == 0 && i < 32) {
            // prefetch next chunk's x (wraps at end; extras unused)
#pragma unroll
            for (int k2 = 0; k2 < 16; ++k2)
                xn[k2] = xrow[((i + 1) * 16 + k2) & 511];
#pragma unroll
            for (int j = 0; j < 16; ++j) {
                const int p = i * 16 + j;
                const float xt = xc[j];
                f32x4 c0;
                c0[0] = fmaf(wih0q[0], xt, b0q[0]);
                c0[1] = fmaf(wih0q[1], xt, b0q[1]);
                c0[2] = fmaf(wih0q[2], xt, b0q[2]);
                c0[3] = fmaf(wih0q[3], xt, b0q[3]);
                f32x4 a = __builtin_amdgcn_mfma_f32_16x16x16f16(Ahh0, Bh0, c0, 0, 0, 0);
                f16x2 p0 = __builtin_amdgcn_cvt_pkrtz(tanh_fast(a[0]), tanh_fast(a[1]));
                f16x2 p1 = __builtin_amdgcn_cvt_pkrtz(tanh_fast(a[2]), tanh_fast(a[3]));
                Bh0 = __builtin_shufflevector(p0, p1, 0, 1, 2, 3);
                h0slot[p & 31][lane] = __builtin_bit_cast(unsigned long long, Bh0);
            }
#pragma unroll
            for (int k2 = 0; k2 < 16; ++k2) xc[k2] = xn[k2];
        }
        if (wid == 1 && i >= 1) {
            const int c = i - 1;
            h0cur = __builtin_bit_cast(f16x4, h0slot[(c * 16) & 31][lane]);
            unsigned long long h0n_ = 0;
#pragma unroll
            for (int j = 0; j < 16; ++j) {
                // prefetch next step's H0 (same chunk only; j=15 reads at
                // next body start, after the barrier -> no race)
                if (j < 15) h0n_ = h0slot[(c * 16 + j + 1) & 31][lane];
                f32x4 d = __builtin_amdgcn_mfma_f32_16x16x16f16(Aih1, h0cur, cb1, 0, 0, 0);
                f32x4 e = __builtin_amdgcn_mfma_f32_16x16x16f16(Ahh1, Bh1, zero4, 0, 0, 0);
                u0 = tanh_fast(d[0] + e[0]);
                u1 = tanh_fast(d[1] + e[1]);
                u2 = tanh_fast(d[2] + e[2]);
                u3 = tanh_fast(d[3] + e[3]);
                f16x2 r0 = __builtin_amdgcn_cvt_pkrtz(u0, u1);
                f16x2 r1 = __builtin_amdgcn_cvt_pkrtz(u2, u3);
                Bh1 = __builtin_shufflevector(r0, r1, 0, 1, 2, 3);
                if (j < 15) h0cur = __builtin_bit_cast(f16x4, h0n_);
            }
        }
        __syncthreads();
    }

    // ---- epilogue (wave1): out = Wfc . H1[511] + bfc ----
    if (wid == 1) {
        float v = u0 * wfcq[0] + u1 * wfcq[1] + u2 * wfcq[2] + u3 * wfcq[3];
        v += __shfl_xor(v, 16, 64);
        v += __shfl_xor(v, 32, 64);
        if (lane < 16) out[b0 + lane] = v + bfc[0];
    }
}

extern "C" void kernel_launch(void* const* d_in, const int* in_sizes, int n_in,
                              void* d_out, int out_size, void* d_ws, size_t ws_size,
                              hipStream_t stream) {
    const float* x    = (const float*)d_in[0];
    const float* Wih0 = (const float*)d_in[1];
    const float* Whh0 = (const float*)d_in[2];
    const float* bih0 = (const float*)d_in[3];
    const float* bhh0 = (const float*)d_in[4];
    const float* Wih1 = (const float*)d_in[5];
    const float* Whh1 = (const float*)d_in[6];
    const float* bih1 = (const float*)d_in[7];
    const float* bhh1 = (const float*)d_in[8];
    const float* Wfc  = (const float*)d_in[9];
    const float* bfc  = (const float*)d_in[10];
    float* out = (float*)d_out;

    rnn2_pipek<<<dim3(512), dim3(128), 0, stream>>>(
        x, Wih0, Whh0, bih0, bhh0, Wih1, Whh1, bih1, bhh1, Wfc, bfc, out);
}